// Round 1
// baseline (1536.522 us; speedup 1.0000x reference)
//
#include <hip/hip_runtime.h>
#include <hip/hip_bf16.h>

typedef __attribute__((ext_vector_type(8))) short short8;
typedef __attribute__((ext_vector_type(4))) float f32x4;

typedef const void __attribute__((address_space(1)))* gptr_t;
typedef void __attribute__((address_space(3)))* sptr_t;

static __device__ __forceinline__ void gload_lds16(const void* g, void* l) {
  __builtin_amdgcn_global_load_lds((gptr_t)g, (sptr_t)l, 16, 0, 0);
}

static __device__ __forceinline__ unsigned short f2bf(float f) {
  unsigned int u = __float_as_uint(f);
  unsigned int r = (u + 0x7fffu + ((u >> 16) & 1u)) >> 16;
  return (unsigned short)r;
}
static __device__ __forceinline__ float bf2f(unsigned short b) {
  return __uint_as_float(((unsigned int)b) << 16);
}

// ---------------- fp32 -> bf16 (same layout) ----------------
__global__ void cvt_f32_to_bf16(const float* __restrict__ in,
                                unsigned short* __restrict__ out, int n) {
  int idx = blockIdx.x * blockDim.x + threadIdx.x;
  int stride = gridDim.x * blockDim.x;
  for (int i = idx * 4; i < n; i += stride * 4) {
    const float4 v = *reinterpret_cast<const float4*>(in + i);
    unsigned long long packed =
        (unsigned long long)f2bf(v.x) | ((unsigned long long)f2bf(v.y) << 16) |
        ((unsigned long long)f2bf(v.z) << 32) | ((unsigned long long)f2bf(v.w) << 48);
    *reinterpret_cast<unsigned long long*>(out + i) = packed;
  }
}

// ---------------- fp32 [K][N] -> bf16 [N][K] (convert + transpose) ----------------
__global__ void cvt_transpose_bf16(const float* __restrict__ in,
                                   unsigned short* __restrict__ out, int K, int N) {
  __shared__ unsigned short tile[32][33];
  int kt = blockIdx.y * 32, nt = blockIdx.x * 32;
  int tx = threadIdx.x & 31;
  int ty = threadIdx.x >> 5;  // 0..7
  #pragma unroll
  for (int i = 0; i < 32; i += 8)
    tile[ty + i][tx] = f2bf(in[(size_t)(kt + ty + i) * N + nt + tx]);
  __syncthreads();
  #pragma unroll
  for (int i = 0; i < 32; i += 8)
    out[(size_t)(nt + ty + i) * K + kt + tx] = tile[tx][ty + i];
}

// ---------------- V [4096][8*128] -> VT [2][8][128][2048] ----------------
__global__ void transpose_v(const unsigned short* __restrict__ Vp,
                            unsigned short* __restrict__ VT) {
  __shared__ unsigned short tile[32][33];
  int st = blockIdx.x * 32;
  int dt = blockIdx.y * 32;
  int bh = blockIdx.z;
  int b = bh >> 3, h = bh & 7;
  int tx = threadIdx.x & 31, ty = threadIdx.x >> 5;
  #pragma unroll
  for (int i = 0; i < 32; i += 8)
    tile[ty + i][tx] = Vp[(size_t)(b * 2048 + st + ty + i) * 1024 + h * 128 + dt + tx];
  __syncthreads();
  #pragma unroll
  for (int i = 0; i < 32; i += 8)
    VT[(size_t)((b * 8 + h) * 128 + dt + ty + i) * 2048 + st + tx] = tile[tx][ty + i];
}

// ---------------- RoPE in place on bf16 [rows][nheads*128] ----------------
__global__ void rope_kernel(unsigned short* __restrict__ buf, int rows, int nheads,
                            int rowstride) {
  int total = rows * nheads * 64;
  int idx = blockIdx.x * blockDim.x + threadIdx.x;
  if (idx >= total) return;
  int j = idx & 63;
  int hh = (idx >> 6) % nheads;
  int r = idx / (64 * nheads);
  int pos = r & 2047;
  float inv = expf(-(float)j * 0.14391157f);  // ln(10000)/64
  float ang = (float)pos * inv;
  float s, c;
  sincosf(ang, &s, &c);
  unsigned int* p =
      reinterpret_cast<unsigned int*>(buf + (size_t)r * rowstride + hh * 128 + 2 * j);
  unsigned int pv = *p;
  float x0 = bf2f((unsigned short)(pv & 0xffffu));
  float x1 = bf2f((unsigned short)(pv >> 16));
  float o0 = x0 * c - x1 * s;
  float o1 = x0 * s + x1 * c;
  *p = (unsigned int)f2bf(o0) | ((unsigned int)f2bf(o1) << 16);
}

// ---------------- GEMM: C[M][N] = A[M][K] * BT[N][K]^T  (bf16 in, fp32 acc) ----------
static __device__ __forceinline__ void store_out(unsigned short* C, size_t idx, float v) {
  C[idx] = f2bf(v);
}
static __device__ __forceinline__ void store_out(float* C, size_t idx, float v) {
  C[idx] = v;
}

template <typename OutT>
__global__ __launch_bounds__(256) void gemm_bt(const unsigned short* __restrict__ A,
                                               const unsigned short* __restrict__ BT,
                                               OutT* __restrict__ C, int M, int N, int K) {
  __shared__ __align__(16) unsigned short As[128 * 32];
  __shared__ __align__(16) unsigned short Bs[128 * 32];
  const int tid = threadIdx.x;
  const int wave = tid >> 6;
  const int lane = tid & 63;
  const int brow = blockIdx.y, bcol = blockIdx.x;
  const int wr = wave >> 1, wc = wave & 1;

  // staging: chunk c covers rows c*16..c*16+15 of the [128][32] tile
  const int srow = wave * 16 + (lane >> 2);
  const int scol = (lane & 3) * 8;
  const unsigned short* gA0 = A + (size_t)(brow * 128 + srow) * K + scol;
  const unsigned short* gA1 = gA0 + (size_t)64 * K;
  const unsigned short* gB0 = BT + (size_t)(bcol * 128 + srow) * K + scol;
  const unsigned short* gB1 = gB0 + (size_t)64 * K;
  unsigned short* lA0 = As + wave * 512;
  unsigned short* lA1 = As + (4 + wave) * 512;
  unsigned short* lB0 = Bs + wave * 512;
  unsigned short* lB1 = Bs + (4 + wave) * 512;

  f32x4 acc[4][4] = {};
  const int fr = lane & 15, fg = lane >> 4;

  for (int kb = 0; kb < K; kb += 32) {
    __syncthreads();
    gload_lds16(gA0 + kb, lA0);
    gload_lds16(gA1 + kb, lA1);
    gload_lds16(gB0 + kb, lB0);
    gload_lds16(gB1 + kb, lB1);
    __syncthreads();
    short8 a[4], b[4];
    #pragma unroll
    for (int i = 0; i < 4; i++)
      a[i] = *reinterpret_cast<const short8*>(&As[(wr * 64 + i * 16 + fr) * 32 + fg * 8]);
    #pragma unroll
    for (int j = 0; j < 4; j++)
      b[j] = *reinterpret_cast<const short8*>(&Bs[(wc * 64 + j * 16 + fr) * 32 + fg * 8]);
    #pragma unroll
    for (int i = 0; i < 4; i++)
      #pragma unroll
      for (int j = 0; j < 4; j++)
        acc[i][j] = __builtin_amdgcn_mfma_f32_16x16x32_bf16(a[i], b[j], acc[i][j], 0, 0, 0);
  }

  #pragma unroll
  for (int i = 0; i < 4; i++)
    #pragma unroll
    for (int j = 0; j < 4; j++)
      #pragma unroll
      for (int r = 0; r < 4; r++) {
        int row = brow * 128 + wr * 64 + i * 16 + fg * 4 + r;
        int col = bcol * 128 + wc * 64 + j * 16 + fr;
        store_out(C, (size_t)row * N + col, acc[i][j][r]);
      }
}

// ---------------- Flash attention (causal, GQA) ----------------
// Q: [4096][4096] roped bf16 (row = b*2048+s, col = h*128+d)
// K: [4096][1024] roped bf16
// VT: [2][8][128][2048] bf16
// O: [4096][4096] bf16
__global__ __launch_bounds__(256) void flash_attn(const unsigned short* __restrict__ Q,
                                                  const unsigned short* __restrict__ K,
                                                  const unsigned short* __restrict__ VT,
                                                  unsigned short* __restrict__ O) {
  __shared__ __align__(16) unsigned short P_lds[4][16][40];
  const int wave = threadIdx.x >> 6, lane = threadIdx.x & 63;
  const int qt = blockIdx.x;  // 0..31
  const int h = blockIdx.y;   // 0..31
  const int b = blockIdx.z;   // 0..1
  const int kvh = h >> 2;
  const int qw = qt * 64 + wave * 16;

  const unsigned short* Qb = Q + (size_t)(b * 2048) * 4096 + h * 128;
  const unsigned short* Kb = K + (size_t)(b * 2048) * 1024 + kvh * 128;
  const unsigned short* Vb = VT + (size_t)((b * 8 + kvh) * 128) * 2048;

  const int fr = lane & 15, fg = lane >> 4;

  short8 qf[4];
  #pragma unroll
  for (int dk = 0; dk < 4; dk++)
    qf[dk] = *reinterpret_cast<const short8*>(&Qb[(size_t)(qw + fr) * 4096 + dk * 32 + fg * 8]);

  float mrow[4], lrow[4];
  #pragma unroll
  for (int r = 0; r < 4; r++) {
    mrow[r] = -INFINITY;
    lrow[r] = 0.f;
  }
  f32x4 oacc[8] = {};

  const float scale = 0.08838834764831845f;  // 1/sqrt(128)

  for (int kb = 0; kb < qw + 16; kb += 32) {
    f32x4 s[2] = {};
    #pragma unroll
    for (int kc = 0; kc < 2; kc++) {
      #pragma unroll
      for (int dk = 0; dk < 4; dk++) {
        short8 kf = *reinterpret_cast<const short8*>(
            &Kb[(size_t)(kb + kc * 16 + fr) * 1024 + dk * 32 + fg * 8]);
        s[kc] = __builtin_amdgcn_mfma_f32_16x16x32_bf16(qf[dk], kf, s[kc], 0, 0, 0);
      }
    }
    // mask + online softmax (rows fg*4+r, key cols fr / 16+fr)
    #pragma unroll
    for (int r = 0; r < 4; r++) {
      int qi = qw + fg * 4 + r;
      float s0 = s[0][r] * scale, s1 = s[1][r] * scale;
      if (kb + fr > qi) s0 = -INFINITY;
      if (kb + 16 + fr > qi) s1 = -INFINITY;
      float mx = fmaxf(s0, s1);
      mx = fmaxf(mx, __shfl_xor(mx, 1));
      mx = fmaxf(mx, __shfl_xor(mx, 2));
      mx = fmaxf(mx, __shfl_xor(mx, 4));
      mx = fmaxf(mx, __shfl_xor(mx, 8));
      float mnew = fmaxf(mrow[r], mx);
      float alpha = __expf(mrow[r] - mnew);
      float p0 = __expf(s0 - mnew);
      float p1 = __expf(s1 - mnew);
      float rs = p0 + p1;
      rs += __shfl_xor(rs, 1);
      rs += __shfl_xor(rs, 2);
      rs += __shfl_xor(rs, 4);
      rs += __shfl_xor(rs, 8);
      lrow[r] = lrow[r] * alpha + rs;
      mrow[r] = mnew;
      #pragma unroll
      for (int dt = 0; dt < 8; dt++) oacc[dt][r] *= alpha;
      P_lds[wave][fg * 4 + r][fr] = f2bf(p0);
      P_lds[wave][fg * 4 + r][16 + fr] = f2bf(p1);
    }
    short8 pf = *reinterpret_cast<const short8*>(&P_lds[wave][fr][fg * 8]);
    #pragma unroll
    for (int dt = 0; dt < 8; dt++) {
      short8 vf = *reinterpret_cast<const short8*>(
          &Vb[(size_t)(dt * 16 + fr) * 2048 + kb + fg * 8]);
      oacc[dt] = __builtin_amdgcn_mfma_f32_16x16x32_bf16(pf, vf, oacc[dt], 0, 0, 0);
    }
  }

  #pragma unroll
  for (int dt = 0; dt < 8; dt++)
    #pragma unroll
    for (int r = 0; r < 4; r++) {
      int row = qw + fg * 4 + r;
      float v = oacc[dt][r] / lrow[r];
      O[(size_t)(b * 2048 + row) * 4096 + h * 128 + dt * 16 + fr] = f2bf(v);
    }
}

// ---------------- launcher ----------------
extern "C" void kernel_launch(void* const* d_in, const int* in_sizes, int n_in,
                              void* d_out, int out_size, void* d_ws, size_t ws_size,
                              hipStream_t stream) {
  const float* x = (const float*)d_in[0];
  const float* Wq = (const float*)d_in[1];
  const float* Wk = (const float*)d_in[2];
  const float* Wv = (const float*)d_in[3];
  const float* Wo = (const float*)d_in[4];
  float* out = (float*)d_out;

  char* ws = (char*)d_ws;
  unsigned short* xb  = (unsigned short*)(ws + 0);          // 32 MB
  unsigned short* WqT = (unsigned short*)(ws + 33554432);   // 32 MB
  unsigned short* WkT = (unsigned short*)(ws + 67108864);   // 8 MB
  unsigned short* WvT = (unsigned short*)(ws + 75497472);   // 8 MB
  unsigned short* WoT = (unsigned short*)(ws + 83886080);   // 32 MB
  unsigned short* Qb  = (unsigned short*)(ws + 117440512);  // 32 MB
  unsigned short* Kp  = (unsigned short*)(ws + 150994944);  // 8 MB
  unsigned short* Vp  = (unsigned short*)(ws + 159383552);  // 8 MB
  unsigned short* VT  = (unsigned short*)(ws + 167772160);  // 8 MB
  unsigned short* Ob  = (unsigned short*)(ws + 176160768);  // 32 MB -> total 200 MB

  cvt_f32_to_bf16<<<2048, 256, 0, stream>>>(x, xb, 4096 * 4096);
  cvt_transpose_bf16<<<dim3(128, 128), 256, 0, stream>>>(Wq, WqT, 4096, 4096);
  cvt_transpose_bf16<<<dim3(32, 128), 256, 0, stream>>>(Wk, WkT, 4096, 1024);
  cvt_transpose_bf16<<<dim3(32, 128), 256, 0, stream>>>(Wv, WvT, 4096, 1024);
  cvt_transpose_bf16<<<dim3(128, 128), 256, 0, stream>>>(Wo, WoT, 4096, 4096);

  gemm_bt<unsigned short><<<dim3(32, 32), 256, 0, stream>>>(xb, WqT, Qb, 4096, 4096, 4096);
  gemm_bt<unsigned short><<<dim3(8, 32), 256, 0, stream>>>(xb, WkT, Kp, 4096, 1024, 4096);
  gemm_bt<unsigned short><<<dim3(8, 32), 256, 0, stream>>>(xb, WvT, Vp, 4096, 1024, 4096);

  rope_kernel<<<(4096 * 32 * 64 + 255) / 256, 256, 0, stream>>>(Qb, 4096, 32, 4096);
  rope_kernel<<<(4096 * 8 * 64 + 255) / 256, 256, 0, stream>>>(Kp, 4096, 8, 1024);

  transpose_v<<<dim3(64, 4, 16), 256, 0, stream>>>(Vp, VT);

  flash_attn<<<dim3(32, 32, 2), 256, 0, stream>>>(Qb, Kp, VT, Ob);

  gemm_bt<float><<<dim3(32, 32), 256, 0, stream>>>(Ob, WoT, out, 4096, 4096, 4096);
}

// Round 3
// 1037.399 us; speedup vs baseline: 1.4811x; 1.4811x over previous
//
#include <hip/hip_runtime.h>
#include <hip/hip_bf16.h>

typedef __attribute__((ext_vector_type(8))) short short8;
typedef __attribute__((ext_vector_type(4))) float f32x4;

typedef const void __attribute__((address_space(1)))* gptr_t;
typedef void __attribute__((address_space(3)))* sptr_t;

static __device__ __forceinline__ void gload_lds16(const void* g, void* l) {
  __builtin_amdgcn_global_load_lds((gptr_t)g, (sptr_t)l, 16, 0, 0);
}

static __device__ __forceinline__ unsigned short f2bf(float f) {
  unsigned int u = __float_as_uint(f);
  unsigned int r = (u + 0x7fffu + ((u >> 16) & 1u)) >> 16;
  return (unsigned short)r;
}
static __device__ __forceinline__ float bf2f(unsigned short b) {
  return __uint_as_float(((unsigned int)b) << 16);
}
// pack 2 f32 -> 2 bf16 in one u32 (v_cvt_pk_bf16_f32, RNE)
static __device__ __forceinline__ unsigned int cvt_pk_bf16(float lo, float hi) {
  unsigned int r;
  asm("v_cvt_pk_bf16_f32 %0, %1, %2" : "=v"(r) : "v"(lo), "v"(hi));
  return r;
}

// ---------------- fp32 -> bf16 (same layout) ----------------
__global__ void cvt_f32_to_bf16(const float* __restrict__ in,
                                unsigned short* __restrict__ out, int n) {
  int idx = blockIdx.x * blockDim.x + threadIdx.x;
  int stride = gridDim.x * blockDim.x;
  for (int i = idx * 4; i < n; i += stride * 4) {
    const float4 v = *reinterpret_cast<const float4*>(in + i);
    unsigned long long packed =
        (unsigned long long)f2bf(v.x) | ((unsigned long long)f2bf(v.y) << 16) |
        ((unsigned long long)f2bf(v.z) << 32) | ((unsigned long long)f2bf(v.w) << 48);
    *reinterpret_cast<unsigned long long*>(out + i) = packed;
  }
}

// ---------------- fp32 [K][N] -> bf16 [N][K] (convert + transpose) ----------------
__global__ void cvt_transpose_bf16(const float* __restrict__ in,
                                   unsigned short* __restrict__ out, int K, int N) {
  __shared__ unsigned short tile[32][33];
  int kt = blockIdx.y * 32, nt = blockIdx.x * 32;
  int tx = threadIdx.x & 31;
  int ty = threadIdx.x >> 5;  // 0..7
  #pragma unroll
  for (int i = 0; i < 32; i += 8)
    tile[ty + i][tx] = f2bf(in[(size_t)(kt + ty + i) * N + nt + tx]);
  __syncthreads();
  #pragma unroll
  for (int i = 0; i < 32; i += 8)
    out[(size_t)(nt + ty + i) * K + kt + tx] = tile[tx][ty + i];
}

// ---------------- V [4096][8*128] -> VT [2][8][128][2048] ----------------
__global__ void transpose_v(const unsigned short* __restrict__ Vp,
                            unsigned short* __restrict__ VT) {
  __shared__ unsigned short tile[32][33];
  int st = blockIdx.x * 32;
  int dt = blockIdx.y * 32;
  int bh = blockIdx.z;
  int b = bh >> 3, h = bh & 7;
  int tx = threadIdx.x & 31, ty = threadIdx.x >> 5;
  #pragma unroll
  for (int i = 0; i < 32; i += 8)
    tile[ty + i][tx] = Vp[(size_t)(b * 2048 + st + ty + i) * 1024 + h * 128 + dt + tx];
  __syncthreads();
  #pragma unroll
  for (int i = 0; i < 32; i += 8)
    VT[(size_t)((b * 8 + h) * 128 + dt + ty + i) * 2048 + st + tx] = tile[tx][ty + i];
}

// ---------------- RoPE in place on bf16 [rows][nheads*128], with output scale ------
__global__ void rope_kernel(unsigned short* __restrict__ buf, int rows, int nheads,
                            int rowstride, float oscale) {
  int total = rows * nheads * 64;
  int idx = blockIdx.x * blockDim.x + threadIdx.x;
  if (idx >= total) return;
  int j = idx & 63;
  int hh = (idx >> 6) % nheads;
  int r = idx / (64 * nheads);
  int pos = r & 2047;
  float inv = expf(-(float)j * 0.14391157f);  // ln(10000)/64
  float ang = (float)pos * inv;
  float s, c;
  sincosf(ang, &s, &c);
  unsigned int* p =
      reinterpret_cast<unsigned int*>(buf + (size_t)r * rowstride + hh * 128 + 2 * j);
  unsigned int pv = *p;
  float x0 = bf2f((unsigned short)(pv & 0xffffu));
  float x1 = bf2f((unsigned short)(pv >> 16));
  float o0 = (x0 * c - x1 * s) * oscale;
  float o1 = (x0 * s + x1 * c) * oscale;
  *p = (unsigned int)f2bf(o0) | ((unsigned int)f2bf(o1) << 16);
}

// ---------------- GEMM: C[M][N] = A[M][K] * BT[N][K]^T  (bf16 in, fp32 acc) ----------
static __device__ __forceinline__ void store_out(unsigned short* C, size_t idx, float v) {
  C[idx] = f2bf(v);
}
static __device__ __forceinline__ void store_out(float* C, size_t idx, float v) {
  C[idx] = v;
}

template <typename OutT>
__global__ __launch_bounds__(256) void gemm_bt(const unsigned short* __restrict__ A,
                                               const unsigned short* __restrict__ BT,
                                               OutT* __restrict__ C, int M, int N, int K) {
  __shared__ __align__(16) unsigned short As[128 * 32];
  __shared__ __align__(16) unsigned short Bs[128 * 32];
  const int tid = threadIdx.x;
  const int wave = tid >> 6;
  const int lane = tid & 63;
  const int brow = blockIdx.y, bcol = blockIdx.x;
  const int wr = wave >> 1, wc = wave & 1;

  const int srow = wave * 16 + (lane >> 2);
  const int scol = (lane & 3) * 8;
  const unsigned short* gA0 = A + (size_t)(brow * 128 + srow) * K + scol;
  const unsigned short* gA1 = gA0 + (size_t)64 * K;
  const unsigned short* gB0 = BT + (size_t)(bcol * 128 + srow) * K + scol;
  const unsigned short* gB1 = gB0 + (size_t)64 * K;
  unsigned short* lA0 = As + wave * 512;
  unsigned short* lA1 = As + (4 + wave) * 512;
  unsigned short* lB0 = Bs + wave * 512;
  unsigned short* lB1 = Bs + (4 + wave) * 512;

  f32x4 acc[4][4] = {};
  const int fr = lane & 15, fg = lane >> 4;

  for (int kb = 0; kb < K; kb += 32) {
    __syncthreads();
    gload_lds16(gA0 + kb, lA0);
    gload_lds16(gA1 + kb, lA1);
    gload_lds16(gB0 + kb, lB0);
    gload_lds16(gB1 + kb, lB1);
    __syncthreads();
    short8 a[4], b[4];
    #pragma unroll
    for (int i = 0; i < 4; i++)
      a[i] = *reinterpret_cast<const short8*>(&As[(wr * 64 + i * 16 + fr) * 32 + fg * 8]);
    #pragma unroll
    for (int j = 0; j < 4; j++)
      b[j] = *reinterpret_cast<const short8*>(&Bs[(wc * 64 + j * 16 + fr) * 32 + fg * 8]);
    #pragma unroll
    for (int i = 0; i < 4; i++)
      #pragma unroll
      for (int j = 0; j < 4; j++)
        acc[i][j] = __builtin_amdgcn_mfma_f32_16x16x32_bf16(a[i], b[j], acc[i][j], 0, 0, 0);
  }

  #pragma unroll
  for (int i = 0; i < 4; i++)
    #pragma unroll
    for (int j = 0; j < 4; j++)
      #pragma unroll
      for (int r = 0; r < 4; r++) {
        int row = brow * 128 + wr * 64 + i * 16 + fg * 4 + r;
        int col = bcol * 128 + wc * 64 + j * 16 + fr;
        store_out(C, (size_t)row * N + col, acc[i][j][r]);
      }
}

// ---------------- Flash attention (causal, GQA), swapped-QK^T 32-rows/wave ----------
// Stats (mrow/lrow/alpha) live in "q = fr" lane domain; oacc rows live in
// "q = fg*4+r" domain -> every rescale/normalize must cross via __shfl.
// Q: [4096][4096] roped bf16, PRE-SCALED by log2(e)/sqrt(128)
// K: [4096][1024] roped bf16
// VT: [2][8][128][2048] bf16
// O: [4096][4096] bf16
__global__ __launch_bounds__(256) void flash_attn(const unsigned short* __restrict__ Q,
                                                  const unsigned short* __restrict__ K,
                                                  const unsigned short* __restrict__ VT,
                                                  unsigned short* __restrict__ O) {
  // per-wave, per-m P staging: [wave][m][16 q][68 k-shorts (64 + pad)]
  __shared__ __align__(16) unsigned short P_lds[4][2][16][68];
  const int wave = threadIdx.x >> 6, lane = threadIdx.x & 63;
  const int fr = lane & 15, fg = lane >> 4;

  // XCD-bijective swizzle: 1024 blocks, 128 consecutive logical ids per XCD
  const int bid = blockIdx.x;
  const int lid = (bid & 7) * 128 + (bid >> 3);
  const int qt = lid & 15;
  const int h = (lid >> 4) & 31;
  const int b = lid >> 9;
  const int kvh = h >> 2;
  const int qw = qt * 128 + wave * 32;  // this wave's 32 q-rows: [qw, qw+32)

  const unsigned short* Qb = Q + (size_t)(b * 2048) * 4096 + h * 128;
  const unsigned short* Kb = K + (size_t)(b * 2048) * 1024 + kvh * 128;
  const unsigned short* Vb = VT + (size_t)((b * 8 + kvh) * 128) * 2048;

  // Q fragments: rows qw+m*16+fr, d = dk*32+fg*8
  short8 qf[2][4];
  #pragma unroll
  for (int m = 0; m < 2; m++)
    #pragma unroll
    for (int dk = 0; dk < 4; dk++)
      qf[m][dk] = *reinterpret_cast<const short8*>(
          &Qb[(size_t)(qw + m * 16 + fr) * 4096 + dk * 32 + fg * 8]);

  float mrow[2] = {-INFINITY, -INFINITY};
  float lrow[2] = {0.f, 0.f};
  f32x4 oacc[2][8] = {};

  const int qlo = qw & ~63;

  // ---- main loop: 64 keys/step, no masking ----
  for (int kb = 0; kb < qlo; kb += 64) {
    f32x4 s[2][4] = {};  // [m][kc] : S^T, row=k_local=fg*4+r, col=q=fr
    #pragma unroll
    for (int kc = 0; kc < 4; kc++) {
      short8 kf[4];
      #pragma unroll
      for (int dk = 0; dk < 4; dk++)
        kf[dk] = *reinterpret_cast<const short8*>(
            &Kb[(size_t)(kb + kc * 16 + fr) * 1024 + dk * 32 + fg * 8]);
      #pragma unroll
      for (int dk = 0; dk < 4; dk++) {
        s[0][kc] = __builtin_amdgcn_mfma_f32_16x16x32_bf16(kf[dk], qf[0][dk], s[0][kc], 0, 0, 0);
        s[1][kc] = __builtin_amdgcn_mfma_f32_16x16x32_bf16(kf[dk], qf[1][dk], s[1][kc], 0, 0, 0);
      }
    }
    #pragma unroll
    for (int m = 0; m < 2; m++) {
      float mx = -INFINITY;
      #pragma unroll
      for (int kc = 0; kc < 4; kc++)
        #pragma unroll
        for (int r = 0; r < 4; r++) mx = fmaxf(mx, s[m][kc][r]);
      mx = fmaxf(mx, __shfl_xor(mx, 16));
      mx = fmaxf(mx, __shfl_xor(mx, 32));
      const bool need = !__all(mx - mrow[m] <= 8.0f);  // defer-max (log2 domain)
      float mnew = need ? fmaxf(mrow[m], mx) : mrow[m];
      if (need) {
        float alpha = exp2f(mrow[m] - mnew);
        lrow[m] *= alpha;
        // oacc rows are q=fg*4+r; alpha is held at lane q=fr -> redistribute
        float alw[4];
        #pragma unroll
        for (int r = 0; r < 4; r++) alw[r] = __shfl(alpha, fg * 4 + r);
        #pragma unroll
        for (int dt = 0; dt < 8; dt++)
          #pragma unroll
          for (int r = 0; r < 4; r++) oacc[m][dt][r] *= alw[r];
      }
      float p[16];
      float rs = 0.f;
      #pragma unroll
      for (int kc = 0; kc < 4; kc++)
        #pragma unroll
        for (int r = 0; r < 4; r++) {
          float pv = exp2f(s[m][kc][r] - mnew);
          p[kc * 4 + r] = pv;
          rs += pv;
        }
      rs += __shfl_xor(rs, 16);
      rs += __shfl_xor(rs, 32);
      lrow[m] += rs;
      mrow[m] = mnew;
      #pragma unroll
      for (int kc = 0; kc < 4; kc++) {
        unsigned int lo = cvt_pk_bf16(p[kc * 4 + 0], p[kc * 4 + 1]);
        unsigned int hi = cvt_pk_bf16(p[kc * 4 + 2], p[kc * 4 + 3]);
        unsigned int* dst =
            reinterpret_cast<unsigned int*>(&P_lds[wave][m][fr][kc * 16 + fg * 4]);
        dst[0] = lo;
        dst[1] = hi;
      }
    }
    #pragma unroll
    for (int c = 0; c < 2; c++) {
      short8 pf0 = *reinterpret_cast<const short8*>(&P_lds[wave][0][fr][c * 32 + fg * 8]);
      short8 pf1 = *reinterpret_cast<const short8*>(&P_lds[wave][1][fr][c * 32 + fg * 8]);
      #pragma unroll
      for (int dt = 0; dt < 8; dt++) {
        short8 vf = *reinterpret_cast<const short8*>(
            &Vb[(size_t)(dt * 16 + fr) * 2048 + kb + c * 32 + fg * 8]);
        oacc[0][dt] = __builtin_amdgcn_mfma_f32_16x16x32_bf16(pf0, vf, oacc[0][dt], 0, 0, 0);
        oacc[1][dt] = __builtin_amdgcn_mfma_f32_16x16x32_bf16(pf1, vf, oacc[1][dt], 0, 0, 0);
      }
    }
  }

  // ---- masked tail: 32 keys/step, covers [qlo, qw+32) ----
  for (int kb = qlo; kb < qw + 32; kb += 32) {
    f32x4 s[2][2] = {};
    #pragma unroll
    for (int kc = 0; kc < 2; kc++) {
      short8 kf[4];
      #pragma unroll
      for (int dk = 0; dk < 4; dk++)
        kf[dk] = *reinterpret_cast<const short8*>(
            &Kb[(size_t)(kb + kc * 16 + fr) * 1024 + dk * 32 + fg * 8]);
      #pragma unroll
      for (int dk = 0; dk < 4; dk++) {
        s[0][kc] = __builtin_amdgcn_mfma_f32_16x16x32_bf16(kf[dk], qf[0][dk], s[0][kc], 0, 0, 0);
        s[1][kc] = __builtin_amdgcn_mfma_f32_16x16x32_bf16(kf[dk], qf[1][dk], s[1][kc], 0, 0, 0);
      }
    }
    #pragma unroll
    for (int m = 0; m < 2; m++) {
      const int qi = qw + m * 16 + fr;
      #pragma unroll
      for (int kc = 0; kc < 2; kc++)
        #pragma unroll
        for (int r = 0; r < 4; r++)
          if (kb + kc * 16 + fg * 4 + r > qi) s[m][kc][r] = -INFINITY;
      float mx = -INFINITY;
      #pragma unroll
      for (int kc = 0; kc < 2; kc++)
        #pragma unroll
        for (int r = 0; r < 4; r++) mx = fmaxf(mx, s[m][kc][r]);
      mx = fmaxf(mx, __shfl_xor(mx, 16));
      mx = fmaxf(mx, __shfl_xor(mx, 32));
      const bool need = !__all(mx - mrow[m] <= 8.0f);
      float mnew = need ? fmaxf(mrow[m], mx) : mrow[m];
      if (need) {
        float alpha = exp2f(mrow[m] - mnew);
        lrow[m] *= alpha;
        float alw[4];
        #pragma unroll
        for (int r = 0; r < 4; r++) alw[r] = __shfl(alpha, fg * 4 + r);
        #pragma unroll
        for (int dt = 0; dt < 8; dt++)
          #pragma unroll
          for (int r = 0; r < 4; r++) oacc[m][dt][r] *= alw[r];
      }
      float p[8];
      float rs = 0.f;
      #pragma unroll
      for (int kc = 0; kc < 2; kc++)
        #pragma unroll
        for (int r = 0; r < 4; r++) {
          float pv = exp2f(s[m][kc][r] - mnew);
          p[kc * 4 + r] = pv;
          rs += pv;
        }
      rs += __shfl_xor(rs, 16);
      rs += __shfl_xor(rs, 32);
      lrow[m] += rs;
      mrow[m] = mnew;
      #pragma unroll
      for (int kc = 0; kc < 2; kc++) {
        unsigned int lo = cvt_pk_bf16(p[kc * 4 + 0], p[kc * 4 + 1]);
        unsigned int hi = cvt_pk_bf16(p[kc * 4 + 2], p[kc * 4 + 3]);
        unsigned int* dst =
            reinterpret_cast<unsigned int*>(&P_lds[wave][m][fr][kc * 16 + fg * 4]);
        dst[0] = lo;
        dst[1] = hi;
      }
    }
    {
      short8 pf0 = *reinterpret_cast<const short8*>(&P_lds[wave][0][fr][fg * 8]);
      short8 pf1 = *reinterpret_cast<const short8*>(&P_lds[wave][1][fr][fg * 8]);
      #pragma unroll
      for (int dt = 0; dt < 8; dt++) {
        short8 vf = *reinterpret_cast<const short8*>(
            &Vb[(size_t)(dt * 16 + fr) * 2048 + kb + fg * 8]);
        oacc[0][dt] = __builtin_amdgcn_mfma_f32_16x16x32_bf16(pf0, vf, oacc[0][dt], 0, 0, 0);
        oacc[1][dt] = __builtin_amdgcn_mfma_f32_16x16x32_bf16(pf1, vf, oacc[1][dt], 0, 0, 0);
      }
    }
  }

  // ---- epilogue: redistribute 1/lrow (held at lane fr=q) to lanes holding q=fg*4+r
  #pragma unroll
  for (int m = 0; m < 2; m++) {
    float linv[4];
    #pragma unroll
    for (int r = 0; r < 4; r++) linv[r] = 1.0f / __shfl(lrow[m], fg * 4 + r);
    #pragma unroll
    for (int dt = 0; dt < 8; dt++)
      #pragma unroll
      for (int r = 0; r < 4; r++) {
        int row = qw + m * 16 + fg * 4 + r;
        float v = oacc[m][dt][r] * linv[r];
        O[(size_t)(b * 2048 + row) * 4096 + h * 128 + dt * 16 + fr] = f2bf(v);
      }
  }
}

// ---------------- launcher ----------------
extern "C" void kernel_launch(void* const* d_in, const int* in_sizes, int n_in,
                              void* d_out, int out_size, void* d_ws, size_t ws_size,
                              hipStream_t stream) {
  const float* x = (const float*)d_in[0];
  const float* Wq = (const float*)d_in[1];
  const float* Wk = (const float*)d_in[2];
  const float* Wv = (const float*)d_in[3];
  const float* Wo = (const float*)d_in[4];
  float* out = (float*)d_out;

  char* ws = (char*)d_ws;
  unsigned short* xb  = (unsigned short*)(ws + 0);          // 32 MB
  unsigned short* WqT = (unsigned short*)(ws + 33554432);   // 32 MB
  unsigned short* WkT = (unsigned short*)(ws + 67108864);   // 8 MB
  unsigned short* WvT = (unsigned short*)(ws + 75497472);   // 8 MB
  unsigned short* WoT = (unsigned short*)(ws + 83886080);   // 32 MB
  unsigned short* Qb  = (unsigned short*)(ws + 117440512);  // 32 MB
  unsigned short* Kp  = (unsigned short*)(ws + 150994944);  // 8 MB
  unsigned short* Vp  = (unsigned short*)(ws + 159383552);  // 8 MB
  unsigned short* VT  = (unsigned short*)(ws + 167772160);  // 8 MB
  unsigned short* Ob  = (unsigned short*)(ws + 176160768);  // 32 MB -> total 200 MB

  cvt_f32_to_bf16<<<2048, 256, 0, stream>>>(x, xb, 4096 * 4096);
  cvt_transpose_bf16<<<dim3(128, 128), 256, 0, stream>>>(Wq, WqT, 4096, 4096);
  cvt_transpose_bf16<<<dim3(32, 128), 256, 0, stream>>>(Wk, WkT, 4096, 1024);
  cvt_transpose_bf16<<<dim3(32, 128), 256, 0, stream>>>(Wv, WvT, 4096, 1024);
  cvt_transpose_bf16<<<dim3(128, 128), 256, 0, stream>>>(Wo, WoT, 4096, 4096);

  gemm_bt<unsigned short><<<dim3(32, 32), 256, 0, stream>>>(xb, WqT, Qb, 4096, 4096, 4096);
  gemm_bt<unsigned short><<<dim3(8, 32), 256, 0, stream>>>(xb, WkT, Kp, 4096, 1024, 4096);
  gemm_bt<unsigned short><<<dim3(8, 32), 256, 0, stream>>>(xb, WvT, Vp, 4096, 1024, 4096);

  // Q pre-scaled by log2(e)/sqrt(HEAD_DIM) so flash softmax runs in exp2 domain
  rope_kernel<<<(4096 * 32 * 64 + 255) / 256, 256, 0, stream>>>(Qb, 4096, 32, 4096,
                                                                0.12751780f);
  rope_kernel<<<(4096 * 8 * 64 + 255) / 256, 256, 0, stream>>>(Kp, 4096, 8, 1024, 1.0f);

  transpose_v<<<dim3(64, 4, 16), 256, 0, stream>>>(Vp, VT);

  flash_attn<<<1024, 256, 0, stream>>>(Qb, Kp, VT, Ob);

  gemm_bt<float><<<dim3(32, 32), 256, 0, stream>>>(Ob, WoT, out, 4096, 4096, 4096);
}